// Round 1
// baseline (216.988 us; speedup 1.0000x reference)
//
#include <hip/hip_runtime.h>
#include <stdint.h>

// Lightning-attention diagonal-block decayed linear attention.
// b=2, h=16, n=8192, d=e=64, BLOCK=64 -> 4096 independent 64x64x64 GEMM pairs.
// Memory-bound: 268 MB fp32 traffic, HBM roofline ~43 us.

#define H_   16
#define N_   8192
#define G_   (N_ / 64)
#define LDSP 72   // padded LDS row stride in bf16 elems (64 + 8 keeps 16B align, 2-way banks)

typedef __attribute__((ext_vector_type(8))) short bf16x8;
typedef __attribute__((ext_vector_type(4))) float f32x4;

static __device__ __forceinline__ unsigned short f2bf(float x) {
    union { float f; uint32_t u; } un; un.f = x;
    uint32_t u = un.u;
    u += 0x7FFFu + ((u >> 16) & 1u);   // round-to-nearest-even
    return (unsigned short)(u >> 16);
}

__global__ __launch_bounds__(256, 4)
void lightning_diag(const float* __restrict__ q,
                    const float* __restrict__ k,
                    const float* __restrict__ v,
                    const float* __restrict__ s,
                    float* __restrict__ out)
{
    __shared__ unsigned short Qs[64 * LDSP];
    __shared__ unsigned short Ks[64 * LDSP];
    __shared__ unsigned short Vt[64 * LDSP];     // V transposed: [e][j]
    __shared__ unsigned short Ss[4][16 * LDSP];  // per-wave S' strip (bf16)

    const int tid  = threadIdx.x;
    const int wave = tid >> 6;
    const int lane = tid & 63;
    const int g16  = lane >> 4;   // lane group 0..3
    const int l16  = lane & 15;

    const int    idx  = blockIdx.x;           // (bi*H + hi)*G + gi
    const int    hi   = (idx / G_) % H_;
    const size_t base = (size_t)idx * 4096;   // 64x64 tile, fully contiguous

    const float sh = s[hi];
    const float c  = -sh * 1.44269504088896f; // -s * log2(e)

    // ---- stage Q, K (row-major bf16) and V^T into LDS ----
    // each tensor tile: 1024 float4; 256 threads -> 4 float4 each, coalesced
    {
        const float4* qg = (const float4*)(q + base);
        const float4* kg = (const float4*)(k + base);
        const float4* vg = (const float4*)(v + base);
        #pragma unroll
        for (int it = 0; it < 4; ++it) {
            const int fi  = tid + it * 256;
            const int row = fi >> 4;          // 16 float4 per 64-elem row
            const int col = (fi & 15) << 2;
            float4 a  = qg[fi];
            float4 b  = kg[fi];
            float4 vv = vg[fi];
            ushort4 qa = make_ushort4(f2bf(a.x), f2bf(a.y), f2bf(a.z), f2bf(a.w));
            ushort4 ka = make_ushort4(f2bf(b.x), f2bf(b.y), f2bf(b.z), f2bf(b.w));
            *(ushort4*)&Qs[row * LDSP + col] = qa;
            *(ushort4*)&Ks[row * LDSP + col] = ka;
            Vt[(col + 0) * LDSP + row] = f2bf(vv.x);
            Vt[(col + 1) * LDSP + row] = f2bf(vv.y);
            Vt[(col + 2) * LDSP + row] = f2bf(vv.z);
            Vt[(col + 3) * LDSP + row] = f2bf(vv.w);
        }
    }
    __syncthreads();

    // ---- GEMM1: S strip (16x64) = Q[wave strip] * K^T ----
    // A-frag: lane holds Q[l16][8*g16 + jj (+32*ks)]; B-frag same pattern on K rows.
    f32x4 acc[4];
    #pragma unroll
    for (int t = 0; t < 4; ++t) acc[t] = (f32x4){0.f, 0.f, 0.f, 0.f};

    const int arow = wave * 16 + l16;
    const bf16x8 a0 = *(const bf16x8*)&Qs[arow * LDSP + g16 * 8];
    const bf16x8 a1 = *(const bf16x8*)&Qs[arow * LDSP + g16 * 8 + 32];
    #pragma unroll
    for (int tc = 0; tc < 4; ++tc) {
        const int brow = tc * 16 + l16;
        const bf16x8 b0 = *(const bf16x8*)&Ks[brow * LDSP + g16 * 8];
        const bf16x8 b1 = *(const bf16x8*)&Ks[brow * LDSP + g16 * 8 + 32];
        acc[tc] = __builtin_amdgcn_mfma_f32_16x16x32_bf16(a0, b0, acc[tc], 0, 0, 0);
        acc[tc] = __builtin_amdgcn_mfma_f32_16x16x32_bf16(a1, b1, acc[tc], 0, 0, 0);
    }

    // ---- decay * causal mask on fp32 acc, write S' strip to LDS (bf16) ----
    // C/D layout (m89-verified): col = lane&15, row = 4*(lane>>4)+reg
    unsigned short* ss = Ss[wave];
    #pragma unroll
    for (int tc = 0; tc < 4; ++tc) {
        #pragma unroll
        for (int r = 0; r < 4; ++r) {
            const int il   = wave * 16 + g16 * 4 + r;  // row in 64-block
            const int jl   = tc * 16 + l16;            // col in 64-block
            const int diff = il - jl;
            const float f  = (diff >= 0) ? exp2f(c * (float)diff) : 0.0f;
            ss[(g16 * 4 + r) * LDSP + jl] = f2bf(acc[tc][r] * f);
        }
    }
    __syncthreads();

    // ---- GEMM2: O strip (16x64) = S' * V ----
    f32x4 oacc[4];
    #pragma unroll
    for (int t = 0; t < 4; ++t) oacc[t] = (f32x4){0.f, 0.f, 0.f, 0.f};
    const bf16x8 sa0 = *(const bf16x8*)&ss[l16 * LDSP + g16 * 8];
    const bf16x8 sa1 = *(const bf16x8*)&ss[l16 * LDSP + g16 * 8 + 32];
    #pragma unroll
    for (int nc = 0; nc < 4; ++nc) {
        const int vrow = nc * 16 + l16;  // e index
        const bf16x8 b0 = *(const bf16x8*)&Vt[vrow * LDSP + g16 * 8];
        const bf16x8 b1 = *(const bf16x8*)&Vt[vrow * LDSP + g16 * 8 + 32];
        oacc[nc] = __builtin_amdgcn_mfma_f32_16x16x32_bf16(sa0, b0, oacc[nc], 0, 0, 0);
        oacc[nc] = __builtin_amdgcn_mfma_f32_16x16x32_bf16(sa1, b1, oacc[nc], 0, 0, 0);
    }

    // ---- store O (fp32), 16-lane 64B contiguous runs ----
    float* og = out + base;
    #pragma unroll
    for (int nc = 0; nc < 4; ++nc) {
        #pragma unroll
        for (int r = 0; r < 4; ++r) {
            og[(wave * 16 + g16 * 4 + r) * 64 + nc * 16 + l16] = oacc[nc][r];
        }
    }
}

extern "C" void kernel_launch(void* const* d_in, const int* in_sizes, int n_in,
                              void* d_out, int out_size, void* d_ws, size_t ws_size,
                              hipStream_t stream) {
    const float* q = (const float*)d_in[0];
    const float* k = (const float*)d_in[1];
    const float* v = (const float*)d_in[2];
    const float* s = (const float*)d_in[3];
    float* out = (float*)d_out;
    const int grid = in_sizes[0] / 4096;  // b*h*G = 4096 tiles
    lightning_diag<<<grid, 256, 0, stream>>>(q, k, v, s, out);
}